// Round 2
// baseline (414.629 us; speedup 1.0000x reference)
//
#include <hip/hip_runtime.h>
#include <hip/hip_bf16.h>
#include <math.h>

#define Gn 16000
#define Bn 4096
#define Ln 64
#define Sn 20000
#define NSPLIT 25   // g-splits in grid.x
#define ITERS 10    // g-blocks per split: NSPLIT*ITERS*64 == Gn

typedef __attribute__((ext_vector_type(8))) short bf16x8;   // 8 bf16 = 4 VGPRs
typedef __attribute__((ext_vector_type(4))) float f32x4;    // MFMA C/D

// ---------- device math helpers ----------

__device__ __forceinline__ float softplus_precise(float z) {
    return fmaxf(z, 0.0f) + log1pf(__expf(-fabsf(z)));
}

// accurate lgamma for z>0 (shift-8 Stirling), used only for the 100-entry table
__device__ __forceinline__ float lgamma_pos8(float z) {
    float p = z * (z + 1.f) * (z + 2.f) * (z + 3.f)
                * (z + 4.f) * (z + 5.f) * (z + 6.f) * (z + 7.f);
    float w = z + 8.f;
    return (w - 0.5f) * __logf(w) - w + 0.9189385332046727f
           + __fdividef(1.0f, 12.0f * w) - __logf(p);
}

__device__ __forceinline__ unsigned short f2bf(float f) {
    union { float f; unsigned int u; } v; v.f = f;
    unsigned int r = v.u + 0x7fff + ((v.u >> 16) & 1);   // RNE
    return (unsigned short)(r >> 16);
}

// async global -> LDS, 16B per lane; lds base must be wave-uniform (HW: base + lane*16)
__device__ __forceinline__ void load_lds16(const void* gsrc, void* lds) {
    __builtin_amdgcn_global_load_lds(
        (const __attribute__((address_space(1))) unsigned int*)gsrc,
        (__attribute__((address_space(3))) unsigned int*)lds,
        16, 0, 0);
}

// ---------- precompute kernels ----------

__global__ void prep_genes(const float* __restrict__ W,
                           const float* __restrict__ px_o,
                           const float* __restrict__ eta,
                           const float* __restrict__ beta,
                           unsigned short* __restrict__ rhB,
                           float4* __restrict__ gcon) {
    int idx = blockIdx.x * 256 + threadIdx.x;   // Gn*64 total, exact
    int g = idx >> 6;
    float bsp = softplus_precise(beta[g]);
    rhB[idx] = f2bf(bsp * softplus_precise(W[idx]));   // W row-major [G][L]
    if (idx < Gn) {
        float o = px_o[idx];
        float4 c;
        c.x = -softplus_precise(-o) - 1.0f;   // log_sigmoid(o) - 1
        c.y = -softplus_precise(o);           // log_sigmoid(-o)
        c.z = softplus_precise(eta[idx]);     // eps
        c.w = 0.f;
        gcon[idx] = c;
    }
}

__global__ void prep_spots(const float* __restrict__ V,
                           const int* __restrict__ ind_x,
                           unsigned short* __restrict__ vBg,
                           float* __restrict__ v64) {
    int idx = blockIdx.x * 256 + threadIdx.x;   // Bn*64 total, exact
    int b = idx >> 6, l = idx & 63;
    int s = ind_x[b];
    vBg[idx] = f2bf(softplus_precise(V[l * Sn + s]));
    if (idx < Bn) {
        int s2 = ind_x[idx];
        v64[idx] = softplus_precise(V[Ln * Sn + s2]);
    }
}

// prior: parallel, atomicAdd into out[Bn+1] (out pre-zeroed by memset)
__global__ void prior_kernel(const float* __restrict__ eta, float* __restrict__ out) {
    int idx = blockIdx.x * 256 + threadIdx.x;
    float s = 0.f;
    if (idx < Gn) {
        float e = eta[idx];
        s = 0.9189385332046727f + 0.5f * e * e;
    }
    #pragma unroll
    for (int off = 32; off; off >>= 1) s += __shfl_xor(s, off, 64);
    __shared__ float red[4];
    if ((threadIdx.x & 63) == 0) red[threadIdx.x >> 6] = s;
    __syncthreads();
    if (threadIdx.x == 0) atomicAdd(&out[Bn + 1], red[0] + red[1] + red[2] + red[3]);
}

// ---------- main kernel ----------
//
// v3: persistent g-loop per block, 2-phase double-buffered prefetch via
// global_load_lds (width 16). LDS dest is linear (HW constraint) so the
// bank-decorrelating permutation is applied on the GLOBAL SOURCE slot
// (slot ^= row&7, 16B granules) and identically on the LDS READ side.
// A-fragments (v tile) hoisted to registers; gene-sum accumulated in
// registers across iters -> one 256B partial store per block, no atomics.
//
// term = lgamma(x+r) - lgamma(r) - lgamma(x+1) + x*lsp + r*lsn
//      ~= (s-0.5)ln s - (r-0.5)ln r + x*(lsp-1) + r*lsn - lfact[x],  s = r+x

__global__ __launch_bounds__(256, 3) void main_kernel(
    const int*            __restrict__ x,
    const unsigned short* __restrict__ rhB,
    const unsigned short* __restrict__ vBg,
    const float*          __restrict__ v64,
    const float4*         __restrict__ gcon,
    float*                __restrict__ partial) {
    __shared__ __align__(16) int            sX[2][64 * 64];   // 2 x 16 KB, source-swizzled
    __shared__ __align__(16) unsigned short sB[2][64 * 64];   // 2 x  8 KB, source-swizzled
    __shared__ float lfact[100];
    __shared__ float pred[64];

    const int tid  = threadIdx.x;
    const int wave = tid >> 6, lane = tid & 63;
    const int quad = lane >> 4, ln = lane & 15;
    const int b0    = blockIdx.y * 64;
    const int gbase = blockIdx.x * ITERS;

    const int mrow = wave * 16 + ln;         // A-fragment m index (b row)
    const int xrow = wave * 16 + quad * 4;   // C rows for this lane (4 regs)

    // block-constant A fragments (v tile) straight into registers
    bf16x8 av[2];
    av[0] = *(const bf16x8*)&vBg[(b0 + mrow) * 64 + 0 * 32 + quad * 8];
    av[1] = *(const bf16x8*)&vBg[(b0 + mrow) * 64 + 1 * 32 + quad * 8];
    float vvr[4];
    #pragma unroll
    for (int r = 0; r < 4; r++) vvr[r] = v64[b0 + xrow + r];

    if (tid < 100) lfact[tid] = lgamma_pos8((float)tid + 1.0f);

    // ---- staging: per-wave global_load_lds, linear LDS dest, swizzled source ----
    // x tile: 64x64 ints, row = 256B = 16 slots of 16B.  4 calls x 4 rows/wave.
    // rh tile: 64x64 bf16, row = 128B = 8 slots of 16B.  2 calls x 8 rows/wave.
#define STAGE(buf, gb) do {                                                        \
        const int g0s = (gb) * 64;                                                 \
        _Pragma("unroll")                                                          \
        for (int c = 0; c < 4; c++) {                                              \
            int rowc = wave * 16 + c * 4 + (lane >> 4);                            \
            int slot = (lane & 15) ^ (rowc & 7);                                   \
            load_lds16(&x[(size_t)(b0 + rowc) * Gn + g0s + slot * 4],              \
                       &sX[buf][(wave * 16 + c * 4) * 64]);                        \
        }                                                                          \
        _Pragma("unroll")                                                          \
        for (int c = 0; c < 2; c++) {                                              \
            int rowc = wave * 16 + c * 8 + (lane >> 3);                            \
            int slot = (lane & 7) ^ (rowc & 7);                                    \
            load_lds16(&rhB[(size_t)(g0s + rowc) * 64 + slot * 8],                 \
                       &sB[buf][(wave * 16 + c * 8) * 64]);                        \
        }                                                                          \
    } while (0)

    STAGE(0, gbase);            // prologue fetch, tile 0
    __syncthreads();            // drains vmcnt (compiler emits full waitcnt)

    float rowacc[4] = {0.f, 0.f, 0.f, 0.f};

    for (int t = 0; t < ITERS; ++t) {
        const int cur = t & 1;
        if (t + 1 < ITERS) STAGE(cur ^ 1, gbase + t + 1);   // prefetch next tile

        const int g0 = (gbase + t) * 64;

        // per-gene constants for this tile (L2-resident, coalesced 16B/lane)
        float4 cc[4];
        #pragma unroll
        for (int nb = 0; nb < 4; nb++) cc[nb] = gcon[g0 + nb * 16 + ln];

        // MFMA: K=64 in two steps, 4 n-blocks
        f32x4 acc[4];
        #pragma unroll
        for (int nb = 0; nb < 4; nb++) acc[nb] = (f32x4){0.f, 0.f, 0.f, 0.f};
        #pragma unroll
        for (int kb = 0; kb < 2; kb++) {
            #pragma unroll
            for (int nb = 0; nb < 4; nb++) {
                const int nbr = nb * 16 + ln;
                const int boff = nbr * 128 + ((kb * 64 + quad * 16) ^ ((nbr & 7) << 4));
                bf16x8 bfr = *(const bf16x8*)((const char*)&sB[cur][0] + boff);
                acc[nb] = __builtin_amdgcn_mfma_f32_16x16x32_bf16(av[kb], bfr, acc[nb], 0, 0, 0);
            }
        }

        // NB epilogue
        #pragma unroll
        for (int nb = 0; nb < 4; nb++) {
            const float lsp1v = cc[nb].x;
            const float lsnv  = cc[nb].y;
            const float ev    = cc[nb].z;
            #pragma unroll
            for (int r = 0; r < 4; r++) {
                const int   row = xrow + r;
                const int   dcol = (nb * 16 + ln) ^ ((row & 7) << 2);
                const int   xi = sX[cur][row * 64 + dcol];
                const float rr = fmaf(ev, vvr[r], acc[nb][r]);   // + eps*v64, fp32
                const float xf = (float)xi;
                const float s  = rr + xf;
                float tt = fmaf(s - 0.5f, __logf(s), -lfact[xi]);
                tt = fmaf(-(rr - 0.5f), __logf(rr), tt);
                tt = fmaf(xf, lsp1v, tt);
                tt = fmaf(rr, lsnv, tt);
                rowacc[r] += tt;
            }
        }

        __syncthreads();   // drains this iter's prefetch AND fences buffer reuse
    }
#undef STAGE

    // reduce over the 16 gene-lanes of each quad; one coalesced store per block
    #pragma unroll
    for (int r = 0; r < 4; r++) {
        float v = rowacc[r];
        v += __shfl_xor(v, 1, 64);
        v += __shfl_xor(v, 2, 64);
        v += __shfl_xor(v, 4, 64);
        v += __shfl_xor(v, 8, 64);
        if (ln == 0) pred[xrow + r] = v;
    }
    __syncthreads();
    if (tid < 64) partial[(size_t)blockIdx.x * Bn + b0 + tid] = pred[tid];
}

// fold partial[NSPLIT][4096] -> out[b] (negated). Direct store, no atomics.
__global__ __launch_bounds__(256) void reduce_kernel(const float* __restrict__ partial,
                                                     float* __restrict__ out) {
    int b = blockIdx.x * 256 + threadIdx.x;
    float s = 0.f;
    #pragma unroll
    for (int i = 0; i < NSPLIT; i++) s += partial[(size_t)i * Bn + b];
    out[b] = -s;
}

// ---------- launch ----------

extern "C" void kernel_launch(void* const* d_in, const int* in_sizes, int n_in,
                              void* d_out, int out_size, void* d_ws, size_t ws_size,
                              hipStream_t stream) {
    const int*   x     = (const int*)d_in[0];
    const int*   ind_x = (const int*)d_in[2];
    const float* W     = (const float*)d_in[3];
    const float* px_o  = (const float*)d_in[4];
    const float* eta   = (const float*)d_in[5];
    const float* V     = (const float*)d_in[6];
    const float* beta  = (const float*)d_in[7];
    float* out = (float*)d_out;

    // ws layout (bytes, all 16B-aligned):
    char* wsb = (char*)d_ws;
    unsigned short* rhB  = (unsigned short*)(wsb);            // Gn*64*2 = 2,048,000
    unsigned short* vBg  = (unsigned short*)(wsb + 2048000);  // Bn*64*2 =   524,288
    float*          v64  = (float*)(wsb + 2572288);           // Bn*4    =    16,384
    float4*         gcon = (float4*)(wsb + 2588672);          // Gn*16   =   256,000
    float*          part = (float*)(wsb + 2844672);           // NSPLIT*Bn*4 = 409,600

    // zero out[Bn] filler slot + prior accumulator (prior uses atomicAdd)
    hipMemsetAsync(d_out, 0, (Bn + 2) * sizeof(float), stream);

    prep_genes<<<(Gn * 64) / 256, 256, 0, stream>>>(W, px_o, eta, beta, rhB, gcon);
    prep_spots<<<(Bn * 64) / 256, 256, 0, stream>>>(V, ind_x, vBg, v64);
    prior_kernel<<<(Gn + 255) / 256, 256, 0, stream>>>(eta, out);

    dim3 grid(NSPLIT, Bn / 64);   // 25 x 64 = 1600 blocks, 10 g-tiles each
    main_kernel<<<grid, 256, 0, stream>>>(x, rhB, vBg, v64, gcon, part);

    reduce_kernel<<<Bn / 256, 256, 0, stream>>>(part, out);
}